// Round 9
// baseline (228.735 us; speedup 1.0000x reference)
//
#include <hip/hip_runtime.h>
#include <stdint.h>

typedef unsigned short u16;
typedef unsigned int u32;
typedef __attribute__((ext_vector_type(8))) short s16x8;
typedef __attribute__((ext_vector_type(8))) __bf16 bf16x8;
typedef __attribute__((ext_vector_type(4))) float f32x4;
typedef __attribute__((ext_vector_type(4))) u32 u32x4;
typedef __attribute__((ext_vector_type(4))) u16 u16x4;

__device__ __forceinline__ u32 f2bf(float f){
  u32 u = __builtin_bit_cast(u32, f);
  return (u + 0x7FFFu + ((u >> 16) & 1u)) >> 16;
}

__device__ __forceinline__ f32x4 mfma16(s16x8 a, s16x8 b, f32x4 c){
  return __builtin_amdgcn_mfma_f32_16x16x32_bf16(
      __builtin_bit_cast(bf16x8, a), __builtin_bit_cast(bf16x8, b), c, 0, 0, 0);
}

__device__ __forceinline__ void gload16(const void* g, void* l){
  __builtin_amdgcn_global_load_lds(
      (const __attribute__((address_space(1))) void*)g,
      (__attribute__((address_space(3))) void*)l, 16, 0, 0);
}

__device__ __forceinline__ u32 cvtpk(float lo, float hi){
  u32 r;
  asm("v_cvt_pk_bf16_f32 %0, %1, %2" : "=v"(r) : "v"(lo), "v"(hi));
  return r;
}

__device__ __forceinline__ float dpp_reduce16(float x){
  float y;
  asm("v_add_f32_dpp %0, %1, %1 row_ror:8 row_mask:0xf bank_mask:0xf"
      : "=&v"(y) : "v"(x));
  asm("v_add_f32_dpp %0, %1, %1 row_ror:4 row_mask:0xf bank_mask:0xf"
      : "=&v"(x) : "v"(y));
  asm("v_add_f32_dpp %0, %1, %1 quad_perm:[2,3,0,1] row_mask:0xf bank_mask:0xf"
      : "=&v"(y) : "v"(x));
  asm("v_add_f32_dpp %0, %1, %1 quad_perm:[1,0,3,2] row_mask:0xf bank_mask:0xf"
      : "=&v"(x) : "v"(y));
  return x;
}

__device__ __forceinline__ void unpack8(s16x8 v, float* f){
  u32x4 u = __builtin_bit_cast(u32x4, v);
  #pragma unroll
  for (int i = 0; i < 4; ++i){
    f[2*i]   = __builtin_bit_cast(float, u[i] << 16);
    f[2*i+1] = __builtin_bit_cast(float, u[i] & 0xffff0000u);
  }
}

// ---------- kprep: X bf16, XTF (transposed frag layout), WF frags, w1/mb ----------
// XTF[b][ct 8][lcg 1024][g 4][l15 16][e 8] = x[row=lcg*32+g*8+e][col=ct*16+l15]
__global__ __launch_bounds__(256) void kprep(
    const float* __restrict__ v, const float* __restrict__ Wk, const float* __restrict__ Wv,
    const float* __restrict__ Wkb, const float* __restrict__ Wvb,
    u16* __restrict__ X, u16* __restrict__ XTF, u16* __restrict__ WF,
    float* __restrict__ w1u, float* __restrict__ scn)
{
  const int tid = threadIdx.x;
  if (blockIdx.x < 512){
    __shared__ u16 sx[128 * 132];
    const int blk = blockIdx.x, b = blk >> 8, lch = blk & 255;
    const float* vb = v + ((size_t)b * 32768 + lch * 128) * 128;
    u16* xb = X + ((size_t)b * 32768 + lch * 128) * 128;
    #pragma unroll
    for (int i = 0; i < 16; ++i){
      int flat = i * 1024 + tid * 4;
      int r = flat >> 7, c = flat & 127;
      float4 f = *(const float4*)(vb + flat);
      u16x4 o; o.x = (u16)f2bf(f.x); o.y = (u16)f2bf(f.y); o.z = (u16)f2bf(f.z); o.w = (u16)f2bf(f.w);
      *(u16x4*)(xb + flat) = o;
      *(u16x4*)(&sx[r * 132 + c]) = o;
    }
    __syncthreads();
    #pragma unroll
    for (int it = 0; it < 8; ++it){
      int t = it * 256 + tid;
      int l15 = t & 15, gg = (t >> 4) & 3, lc = (t >> 6) & 3, ct = t >> 8;
      u16 tmp[8];
      #pragma unroll
      for (int e = 0; e < 8; ++e)
        tmp[e] = sx[(lc * 32 + gg * 8 + e) * 132 + ct * 16 + l15];
      u32 w0 = (u32)tmp[0] | ((u32)tmp[1] << 16);
      u32 w1_ = (u32)tmp[2] | ((u32)tmp[3] << 16);
      u32 w2 = (u32)tmp[4] | ((u32)tmp[5] << 16);
      u32 w3 = (u32)tmp[6] | ((u32)tmp[7] << 16);
      u32x4 uu = {w0, w1_, w2, w3};
      size_t off = ((((size_t)b * 8 + ct) * 1024 + (lch * 4 + lc)) * 4 + gg) * 128 + (size_t)l15 * 8;
      *reinterpret_cast<u32x4*>(XTF + off) = uu;
    }
  } else {
    const int hp = blockIdx.x - 512, h = hp & 7, proj = hp >> 3;
    const float* W = proj ? Wv : Wk;
    const float* pb = (proj ? Wvb : Wkb) + h * 128;
    for (int i = tid; i < 16384; i += 256){
      int e = i & 7, ln = (i >> 3) & 63, ks = (i >> 9) & 3, nt = i >> 11;
      int c = ks * 32 + (ln >> 4) * 8 + e;
      int n = nt * 16 + (ln & 15);
      WF[proj * 131072 + h * 16384 + i] = (u16)f2bf(W[(size_t)c * 1024 + h * 128 + n]);
    }
    if (tid < 128){
      float s = 0.f;
      const float* p = W + (size_t)tid * 1024 + h * 128;
      for (int n = 0; n < 128; ++n) s += p[n];
      w1u[hp * 128 + tid] = s * 0.0078125f;
    }
    if (tid == 0){
      float mb = 0.f;
      for (int n = 0; n < 128; ++n) mb += pb[n];
      scn[hp] = mb * 0.0078125f;
    }
  }
}

// ---------- kstat v3: barrier-free. Each wave: full-row proj (weights in 128 VGPR),
// 16 rows/iter, stats close in-wave via dpp. Waves 0-3: K -> aF; 4-7: V -> bF. ----------
__global__ __launch_bounds__(512, 2) void kstat(
    const u16* __restrict__ X, const u16* __restrict__ WF,
    const float* __restrict__ bk, const float* __restrict__ bv,
    float* __restrict__ aF, float* __restrict__ bF)
{
  const int tid = threadIdx.x, wid = tid >> 6, lane = tid & 63, g = lane >> 4, l15 = lane & 15;
  const int bh = blockIdx.x >> 5, grp = blockIdx.x & 31;
  const int b = bh >> 3, h = bh & 7;
  const int proj = wid >> 2, w4 = wid & 3;

  s16x8 wf[8][4];
  {
    const u16* wbase = WF + proj * 131072 + h * 16384;
    #pragma unroll
    for (int nt = 0; nt < 8; ++nt)
      #pragma unroll
      for (int ks = 0; ks < 4; ++ks)
        wf[nt][ks] = *(const s16x8*)(wbase + (size_t)((nt * 4 + ks) * 512) + lane * 8);
  }
  const float* bias = proj ? bv : bk;
  float br[8];
  #pragma unroll
  for (int nt = 0; nt < 8; ++nt) br[nt] = bias[h * 128 + nt * 16 + l15];

  const u16* Xb = X + (size_t)b * 32768 * 128;
  float* oF = (proj ? bF : aF) + (size_t)bh * 32768;
  const int rb0 = grp * 1024 + w4 * 256;

  s16x8 af[4], afn[4];
  #pragma unroll
  for (int ks = 0; ks < 4; ++ks)
    af[ks] = *(const s16x8*)(Xb + (size_t)(rb0 + l15) * 128 + ks * 32 + g * 8);

  #pragma unroll 1
  for (int it = 0; it < 16; ++it){
    const int rb = rb0 + it * 16;
    #pragma unroll
    for (int ks = 0; ks < 4; ++ks)
      afn[ks] = *(const s16x8*)(Xb + (size_t)(rb + 16 + l15) * 128 + ks * 32 + g * 8);
    f32x4 acc[8];
    #pragma unroll
    for (int nt = 0; nt < 8; ++nt) acc[nt] = f32x4{0.f,0.f,0.f,0.f};
    #pragma unroll
    for (int ks = 0; ks < 4; ++ks)
      #pragma unroll
      for (int nt = 0; nt < 8; ++nt)
        acc[nt] = mfma16(af[ks], wf[nt][ks], acc[nt]);
    f32x4 s4 = {0.f,0.f,0.f,0.f}, q4 = {0.f,0.f,0.f,0.f};
    #pragma unroll
    for (int nt = 0; nt < 8; ++nt){
      f32x4 t = acc[nt] + br[nt];
      s4 += t; q4 += t * t;
    }
    #pragma unroll
    for (int j = 0; j < 4; ++j){
      float ss = dpp_reduce16(s4[j]);
      float qq = dpp_reduce16(q4[j]);
      float mu = ss * 0.0078125f;
      float var = qq * 0.0078125f - mu * mu;
      float rs = rsqrtf(var + 1e-5f);
      if (l15 == g * 4 + j) oF[rb + l15] = rs;
    }
    #pragma unroll
    for (int ks = 0; ks < 4; ++ks) af[ks] = afn[ks];
  }
}

// ---------- kcab: c = a*b (f32) + packed bf16 strip {c,a,b} ----------
__global__ __launch_bounds__(256) void kcab(
    const float* __restrict__ aF, const float* __restrict__ bF,
    float* __restrict__ cF, u16* __restrict__ cab)
{
  int i = (blockIdx.x * 256 + threadIdx.x) * 4;
  if (i >= 524288) return;
  f32x4 a = *(const f32x4*)(aF + i);
  f32x4 b = *(const f32x4*)(bF + i);
  f32x4 c = a * b;
  *(f32x4*)(cF + i) = c;
  int bh = i >> 15, row = i & 32767;
  u16* base = cab + (size_t)bh * 98304 + row;
  u16x4 pc, pa, pb;
  pc.x = (u16)f2bf(c.x); pc.y = (u16)f2bf(c.y); pc.z = (u16)f2bf(c.z); pc.w = (u16)f2bf(c.w);
  pa.x = (u16)f2bf(a.x); pa.y = (u16)f2bf(a.y); pa.z = (u16)f2bf(a.z); pa.w = (u16)f2bf(a.w);
  pb.x = (u16)f2bf(b.x); pb.y = (u16)f2bf(b.y); pb.z = (u16)f2bf(b.z); pb.w = (u16)f2bf(b.w);
  *(u16x4*)(base) = pc;
  *(u16x4*)(base + 32768) = pa;
  *(u16x4*)(base + 65536) = pb;
}

// ---------- kS2 v3: LDS-staged shared tiles; 8 waves = 4 A-pairs x 2 lcg-parities.
// S[bh] += [cX;c;a;b]^T [X|1] via atomics. ----------
__global__ __launch_bounds__(512, 2) void kS2(
    const u16* __restrict__ XTF, const float* __restrict__ cF,
    const u16* __restrict__ cab, float* __restrict__ S)
{
  __shared__ char sbuf[32768];   // 2 x [2 lcg][8 ct][1024 B]
  const int tid = threadIdx.x, wid = tid >> 6, lane = tid & 63, g = lane >> 4, l15 = lane & 15;
  const int bh = blockIdx.x >> 4, grp = blockIdx.x & 15;
  const int b = bh >> 3;
  const int par = wid >> 2, ap = wid & 3;
  const int t0 = 2 * ap, t1 = t0 + 1;
  const char* xtb = (const char*)(XTF + (size_t)b * 4194304);
  const float* cFb = cF + (size_t)bh * 32768;
  const u16* cabb = cab + (size_t)bh * 98304 + (size_t)(l15 < 3 ? l15 : 0) * 32768;
  const int lcg0 = grp * 64;

  f32x4 accC[2][8], accS[2], accB[2], accS8 = {0.f,0.f,0.f,0.f};
  #pragma unroll
  for (int ti = 0; ti < 2; ++ti){
    accS[ti] = f32x4{0.f,0.f,0.f,0.f};
    accB[ti] = f32x4{0.f,0.f,0.f,0.f};
    #pragma unroll
    for (int q = 0; q < 8; ++q) accC[ti][q] = f32x4{0.f,0.f,0.f,0.f};
  }
  s16x8 bone;
  { u32 o = (l15 == 0) ? 0x3F803F80u : 0u; u32x4 t = {o, o, o, o};
    bone = __builtin_bit_cast(s16x8, t); }

#define STAGE(s) { \
    const int le_ = lcg0 + 2 * (s); \
    const char* s0_ = xtb + (size_t)(tid >> 6) * 1048576 + (size_t)le_ * 1024 + (size_t)(tid & 63) * 16; \
    char* d0_ = sbuf + (((s) & 1) << 14) + tid * 16; \
    gload16(s0_, d0_); \
    gload16(s0_ + 1024, d0_ + 8192); \
  }

#define CSTEP(s) { \
    const int ml_ = lcg0 + 2 * (s) + par; \
    const char* tb_ = sbuf + (((s) & 1) << 14) + (par << 13); \
    f32x4 c0_ = *(const f32x4*)(cFb + ml_ * 32 + g * 8); \
    f32x4 c1_ = *(const f32x4*)(cFb + ml_ * 32 + g * 8 + 4); \
    float cs_[8] = {c0_.x, c0_.y, c0_.z, c0_.w, c1_.x, c1_.y, c1_.z, c1_.w}; \
    s16x8 ar0_ = *(const s16x8*)(tb_ + t0 * 1024 + lane * 16); \
    s16x8 ar1_ = *(const s16x8*)(tb_ + t1 * 1024 + lane * 16); \
    s16x8 aS0, aS1; \
    { float fa[8]; unpack8(ar0_, fa); \
      u32x4 pv = {cvtpk(fa[0]*cs_[0], fa[1]*cs_[1]), cvtpk(fa[2]*cs_[2], fa[3]*cs_[3]), \
                  cvtpk(fa[4]*cs_[4], fa[5]*cs_[5]), cvtpk(fa[6]*cs_[6], fa[7]*cs_[7])}; \
      aS0 = __builtin_bit_cast(s16x8, pv); } \
    { float fa[8]; unpack8(ar1_, fa); \
      u32x4 pv = {cvtpk(fa[0]*cs_[0], fa[1]*cs_[1]), cvtpk(fa[2]*cs_[2], fa[3]*cs_[3]), \
                  cvtpk(fa[4]*cs_[4], fa[5]*cs_[5]), cvtpk(fa[6]*cs_[6], fa[7]*cs_[7])}; \
      aS1 = __builtin_bit_cast(s16x8, pv); } \
    s16x8 astr = *(const s16x8*)(cabb + ml_ * 32 + g * 8); \
    if (l15 >= 3){ u32x4 z = {0,0,0,0}; astr = __builtin_bit_cast(s16x8, z); } \
    _Pragma("unroll") for (int q = 0; q < 8; ++q){ \
      s16x8 bq = *(const s16x8*)(tb_ + q * 1024 + lane * 16); \
      accC[0][q] = mfma16(aS0, bq, accC[0][q]); \
      accC[1][q] = mfma16(aS1, bq, accC[1][q]); \
      if (q == t0) accS[0] = mfma16(astr, bq, accS[0]); \
      if (q == t1) accS[1] = mfma16(astr, bq, accS[1]); \
    } \
    accB[0] = mfma16(aS0, bone, accB[0]); \
    accB[1] = mfma16(aS1, bone, accB[1]); \
    if (ap == 0) accS8 = mfma16(astr, bone, accS8); \
  }

  STAGE(0);
  __syncthreads();
  #pragma unroll 1
  for (int s = 0; s < 32; ++s){
    if (s + 1 < 32) STAGE(s + 1);
    CSTEP(s);
    __syncthreads();
  }
#undef CSTEP
#undef STAGE

  float* Sp = S + (size_t)bh * 19008;   // 132 x 144
  #pragma unroll
  for (int ti = 0; ti < 2; ++ti){
    const int t = t0 + ti;
    #pragma unroll
    for (int q = 0; q < 8; ++q)
      #pragma unroll
      for (int j = 0; j < 4; ++j)
        atomicAdd(Sp + (t * 16 + g * 4 + j) * 144 + q * 16 + l15, accC[ti][q][j]);
  }
  if (g == 0){
    #pragma unroll
    for (int j = 0; j < 3; ++j){
      atomicAdd(Sp + (128 + j) * 144 + t0 * 16 + l15, accS[0][j]);
      atomicAdd(Sp + (128 + j) * 144 + t1 * 16 + l15, accS[1][j]);
    }
  }
  if (l15 == 0){
    #pragma unroll
    for (int ti = 0; ti < 2; ++ti)
      #pragma unroll
      for (int j = 0; j < 4; ++j)
        atomicAdd(Sp + ((t0 + ti) * 16 + g * 4 + j) * 144 + 128, accB[ti][j]);
  }
  if (ap == 0 && g == 0 && l15 == 0){
    #pragma unroll
    for (int j = 0; j < 3; ++j)
      atomicAdd(Sp + (128 + j) * 144 + 128, accS8[j]);
  }
}

// ---------- kfoldA: G = W~k^T S2 W~v + rank1 + LN gamma/beta corrections -> AM ----------
__global__ __launch_bounds__(256) void kfoldA(
    const float* __restrict__ S, const float* __restrict__ Wk, const float* __restrict__ Wv,
    const float* __restrict__ Wkb, const float* __restrict__ Wvb,
    const float* __restrict__ w1u, const float* __restrict__ scn,
    const float* __restrict__ gk, const float* __restrict__ bbk,
    const float* __restrict__ gv, const float* __restrict__ bbv,
    float* __restrict__ AM)
{
  extern __shared__ float fsm[];
  float* sA = fsm;                 // [128][129]
  float* sS = fsm + 16512;         // [128][33]
  float* svt = fsm + 20736;        // [32]
  float* svb = fsm + 20768;        // [32]
  float* skt = fsm + 20800;        // [128]
  float* skb = fsm + 20928;        // [128]
  const int blk = blockIdx.x, bh = blk >> 2, es = blk & 3;
  const int h = bh & 7;
  const int tid = threadIdx.x;
  const float* Sg = S + (size_t)bh * 19008;
  const float mbk = scn[h], mbv = scn[8 + h];

  for (int idx = tid; idx < 16384; idx += 256){
    int r = idx >> 7, c = idx & 127;
    sA[r * 129 + c] = Sg[r * 144 + c];
  }
  for (int idx = tid; idx < 4096; idx += 256){
    int c = idx >> 5, j = idx & 31;
    sS[c * 33 + j] = Wv[(size_t)c * 1024 + h * 128 + es * 32 + j] - w1u[(8 + h) * 128 + c];
  }
  __syncthreads();
  if (tid < 32){
    float t = 0.f, tb = 0.f;
    for (int c = 0; c < 128; ++c){
      float wv = sS[c * 33 + tid];
      t  += Sg[128 * 144 + c] * wv;
      tb += Sg[130 * 144 + c] * wv;
    }
    svt[tid] = t;
    svb[tid] = tb + Sg[130 * 144 + 128] * (Wvb[h * 128 + es * 32 + tid] - mbv);
  }
  const int r0 = (tid >> 4) * 8, e0 = (tid & 15) * 2;
  float t8[8][2] = {};
  for (int c = 0; c < 128; ++c){
    float w0 = sS[c * 33 + e0], w1_ = sS[c * 33 + e0 + 1];
    #pragma unroll
    for (int i = 0; i < 8; ++i){
      float a = sA[(r0 + i) * 129 + c];
      t8[i][0] += a * w0; t8[i][1] += a * w1_;
    }
  }
  __syncthreads();
  #pragma unroll
  for (int i = 0; i < 8; ++i){
    sS[(r0 + i) * 33 + e0] = t8[i][0];
    sS[(r0 + i) * 33 + e0 + 1] = t8[i][1];
  }
  for (int idx = tid; idx < 16384; idx += 256){
    int c = idx >> 7, n = idx & 127;
    sA[c * 129 + n] = Wk[(size_t)c * 1024 + h * 128 + n] - w1u[h * 128 + c];
  }
  __syncthreads();
  if (tid < 128){
    float t = 0.f, ta = 0.f;
    for (int c = 0; c < 128; ++c){
      float wk = sA[c * 129 + tid];
      t  += Sg[128 * 144 + c] * wk;
      ta += Sg[129 * 144 + c] * wk;
    }
    skt[tid] = t;
    skb[tid] = ta + Sg[129 * 144 + 128] * (Wkb[h * 128 + tid] - mbk);
  }
  float g8[8][2] = {};
  for (int c = 0; c < 128; ++c){
    float t0 = sS[c * 33 + e0], t1 = sS[c * 33 + e0 + 1];
    #pragma unroll
    for (int i = 0; i < 8; ++i){
      float wk = sA[c * 129 + (r0 + i)];
      g8[i][0] += wk * t0; g8[i][1] += wk * t1;
    }
  }
  __syncthreads();
  const float s0 = Sg[128 * 144 + 128];
  #pragma unroll
  for (int i = 0; i < 8; ++i){
    int n = r0 + i;
    float btk = Wkb[h * 128 + n] - mbk;
    #pragma unroll
    for (int jj = 0; jj < 2; ++jj){
      int j = e0 + jj, dv = es * 32 + j;
      float btv = Wvb[h * 128 + dv] - mbv;
      float G = g8[i][jj] + skt[n] * btv + btk * svt[j] + s0 * btk * btv;
      float am = gk[h*128+n] * (gv[h*128+dv] * G + skb[n] * bbv[h*128+dv])
               + bbk[h*128+n] * (gv[h*128+dv] * svb[j] + 32768.f * bbv[h*128+dv]);
      AM[(size_t)bh * 16384 + n * 128 + dv] = am;
    }
  }
}

// ---------- kfoldB: T1 = AM@Wo ; W4F += frag(Wq@T1)/n ; c4 ----------
__global__ __launch_bounds__(256) void kfoldB(
    const float* __restrict__ AM, const float* __restrict__ Wo,
    const float* __restrict__ Wq, const float* __restrict__ Wq_b,
    const float* __restrict__ Wo_b, float* __restrict__ W4F, float* __restrict__ c4)
{
  extern __shared__ float fsm[];
  float* sA = fsm;
  float* sS = fsm + 128 * 129;
  int blk = blockIdx.x;
  int bh = blk >> 2, eq = blk & 3;
  int b = bh >> 3, hs = bh & 7;
  int tid = threadIdx.x;

  for (int idx = tid; idx < 16384; idx += 256){
    int r = idx >> 7, c = idx & 127;
    sA[r * 129 + c] = AM[(size_t)bh * 16384 + idx];
  }
  for (int idx = tid; idx < 4096; idx += 256){
    int r = idx >> 5, c = idx & 31;
    sS[r * 33 + c] = Wo[(size_t)hs * 16384 + r * 128 + eq * 32 + c];
  }
  __syncthreads();

  int r0 = (tid >> 4) * 8, e0 = (tid & 15) * 2;
  float t8[8][2] = {};
  for (int c = 0; c < 128; ++c){
    float wv0 = sS[c * 33 + e0], wv1 = sS[c * 33 + e0 + 1];
    #pragma unroll
    for (int i = 0; i < 8; ++i){
      float a = sA[(r0 + i) * 129 + c];
      t8[i][0] += a * wv0; t8[i][1] += a * wv1;
    }
  }
  __syncthreads();
  #pragma unroll
  for (int i = 0; i < 8; ++i){
    sS[(r0 + i) * 33 + e0]     = t8[i][0];
    sS[(r0 + i) * 33 + e0 + 1] = t8[i][1];
  }
  for (int idx = tid; idx < 16384; idx += 256){
    int r = idx >> 7, c = idx & 127;
    sA[r * 129 + c] = Wq[(size_t)r * 1024 + hs * 128 + c];
  }
  __syncthreads();

  float a8[8][2] = {};
  for (int d = 0; d < 128; ++d){
    float t0 = sS[d * 33 + e0], t1 = sS[d * 33 + e0 + 1];
    #pragma unroll
    for (int i = 0; i < 8; ++i){
      float w = sA[(r0 + i) * 129 + d];
      a8[i][0] += w * t0; a8[i][1] += w * t1;
    }
  }
  const float inv_n = 0.0009765625f;
  #pragma unroll
  for (int i = 0; i < 8; ++i)
    #pragma unroll
    for (int j = 0; j < 2; ++j){
      int cc = r0 + i, nn = eq * 32 + e0 + j;
      int o = ((nn >> 4) * 4 + (cc >> 5)) * 512 + ((cc >> 3) & 3) * 128
            + (nn & 15) * 8 + (cc & 7);
      atomicAdd(W4F + (size_t)b * 16384 + o, a8[i][j] * inv_n);
    }
  if (tid < 32){
    float s = 0.f;
    for (int d = 0; d < 128; ++d) s += Wq_b[hs * 128 + d] * sS[d * 33 + tid];
    if (hs == 0) s += Wo_b[eq * 32 + tid];
    atomicAdd(c4 + b * 128 + eq * 32 + tid, s * inv_n);
  }
}

// ---------- kout = x @ W4[b] + c4[b] ----------
__global__ __launch_bounds__(256, 4) void kout(
    const u16* __restrict__ X, const float* __restrict__ W4F,
    const float* __restrict__ c4, float* __restrict__ out)
{
  __shared__ char sW[32768];
  const int tid = threadIdx.x, wid = tid >> 6, lane = tid & 63, g = lane >> 4, l15 = lane & 15;
  const int blk = blockIdx.x, b = blk >> 8, ch = blk & 255;
  {
    const float* w4b = W4F + (size_t)b * 16384;
    #pragma unroll
    for (int it2 = 0; it2 < 16; ++it2){
      int idx = it2 * 1024 + tid * 4;
      float4 f = *(const float4*)(w4b + idx);
      uint2 w; w.x = cvtpk(f.x, f.y); w.y = cvtpk(f.z, f.w);
      *(uint2*)(sW + idx * 2) = w;
    }
  }
  const char* xr = (const char*)(X + ((size_t)b * 32768 + ch * 128 + wid * 32 + l15) * 128) + g * 16;
  s16x8 af[2][4];
  #pragma unroll
  for (int mt = 0; mt < 2; ++mt)
    #pragma unroll
    for (int ks = 0; ks < 4; ++ks)
      af[mt][ks] = *(const s16x8*)(xr + mt * 4096 + ks * 64);
  __syncthreads();

  f32x4 acc[2][8];
  #pragma unroll
  for (int mt = 0; mt < 2; ++mt)
    #pragma unroll
    for (int nt = 0; nt < 8; ++nt) acc[mt][nt] = f32x4{0.f, 0.f, 0.f, 0.f};

  const u32 wread = (u32)(lane * 16);
  #pragma unroll
  for (int ks = 0; ks < 4; ++ks)
    #pragma unroll
    for (int nt = 0; nt < 8; ++nt){
      s16x8 wf = *(const s16x8*)(sW + wread + (nt * 4 + ks) * 1024);
      acc[0][nt] = mfma16(af[0][ks], wf, acc[0][nt]);
      acc[1][nt] = mfma16(af[1][ks], wf, acc[1][nt]);
    }
  float* ob = out + ((size_t)b * 32768 + ch * 128 + wid * 32) * 128;
  #pragma unroll
  for (int nt = 0; nt < 8; ++nt){
    float c4v = c4[b * 128 + nt * 16 + l15];
    #pragma unroll
    for (int mt = 0; mt < 2; ++mt)
      #pragma unroll
      for (int j = 0; j < 4; ++j)
        ob[(mt * 16 + g * 4 + j) * 128 + nt * 16 + l15] = acc[mt][nt][j] + c4v;
  }
}

extern "C" void kernel_launch(void* const* d_in, const int* in_sizes, int n_in,
                              void* d_out, int out_size, void* d_ws, size_t ws_size,
                              hipStream_t stream){
  const float* v    = (const float*)d_in[0];
  const float* Wq_w = (const float*)d_in[1];
  const float* Wq_b = (const float*)d_in[2];
  const float* Wk_w = (const float*)d_in[3];
  const float* Wk_b = (const float*)d_in[4];
  const float* Wv_w = (const float*)d_in[5];
  const float* Wv_b = (const float*)d_in[6];
  const float* Wo_w = (const float*)d_in[7];
  const float* Wo_b = (const float*)d_in[8];
  const float* lnk_g = (const float*)d_in[9];
  const float* lnk_b = (const float*)d_in[10];
  const float* lnv_g = (const float*)d_in[11];
  const float* lnv_b = (const float*)d_in[12];

  char* ws = (char*)d_ws;
  u16*   X    = (u16*)  (ws);                 // 16,777,216
  u16*   XTF  = (u16*)  (ws + 16777216);      // 16,777,216
  u16*   WF   = (u16*)  (ws + 33554432);      // 524,288
  float* aF   = (float*)(ws + 34078720);      // 2,097,152
  float* bF   = (float*)(ws + 36175872);      // 2,097,152
  float* cF   = (float*)(ws + 38273024);      // 2,097,152
  u16*   cab  = (u16*)  (ws + 40370176);      // 3,145,728
  float* w1u  = (float*)(ws + 43515904);      // 8,192
  float* scn  = (float*)(ws + 43524096);      // 128 (pad to 43524224)
  float* S    = (float*)(ws + 43524224);      // 1,216,512
  float* W4F  = (float*)(ws + 44740736);      // 131,072
  float* c4   = (float*)(ws + 44871808);      // 1,024
  float* AM   = (float*)(ws + 44872832);      // 1,048,576

  // zero S + W4F + c4 (atomicAdd targets; contiguous)
  hipMemsetAsync(ws + 43524224, 0, 1348608, stream);

  hipLaunchKernelGGL(kprep, dim3(528), dim3(256), 0, stream,
                     v, Wk_w, Wv_w, Wk_b, Wv_b, X, XTF, WF, w1u, scn);

  hipLaunchKernelGGL(kstat, dim3(512), dim3(512), 0, stream,
                     X, WF, Wk_b, Wv_b, aF, bF);

  hipLaunchKernelGGL(kcab, dim3(512), dim3(256), 0, stream, aF, bF, cF, cab);

  hipLaunchKernelGGL(kS2, dim3(256), dim3(512), 0, stream, XTF, cF, cab, S);

  (void)hipFuncSetAttribute((const void*)kfoldA,
                            hipFuncAttributeMaxDynamicSharedMemorySize, 84224);
  hipLaunchKernelGGL(kfoldA, dim3(64), dim3(256), 84224, stream,
                     S, Wk_w, Wv_w, Wk_b, Wv_b, w1u, scn,
                     lnk_g, lnk_b, lnv_g, lnv_b, AM);

  (void)hipFuncSetAttribute((const void*)kfoldB,
                            hipFuncAttributeMaxDynamicSharedMemorySize, 82944);
  hipLaunchKernelGGL(kfoldB, dim3(64), dim3(256), 82944, stream,
                     AM, Wo_w, Wq_w, Wq_b, Wo_b, W4F, c4);

  hipLaunchKernelGGL(kout, dim3(512), dim3(256), 0, stream, X, W4F, c4, (float*)d_out);
}